// Round 1
// baseline (380.103 us; speedup 1.0000x reference)
//
#include <hip/hip_runtime.h>
#include <math.h>

#define NB 16
#define NN 16384
#define DD 128
#define KK 10

// ws layout (floats):
//   hsum : [2][NB][DD]      offset 0       size 4096   (t=0 -> sum over H1 rows, t=1 -> H2)
//   v    : [2][NB][KK][DD]  offset 4096    size 40960  (scale folded in: 1/(N*sqrt(d)))
//   accg : [2][NB][40]      offset 45056   size 1280   ([k]=SE, [10+k]=Yx, [20+k]=Yy, [30+k]=Yz)
#define WS_FLOATS 46336

// ---------------------------------------------------------------------------
// Kernel 1: column sums of H1 and H2 (the means, un-normalized).
// grid 2048 = 2 tensors x 16 batches x 64 chunks of 256 rows. 256 threads.
__global__ __launch_bounds__(256) void k_means(const float* __restrict__ H1,
                                               const float* __restrict__ H2,
                                               float* __restrict__ hsum) {
    int bi = blockIdx.x;
    int t = bi >> 10;
    int rem = bi & 1023;
    int b = rem >> 6;
    int chunk = rem & 63;
    const float* src = (t ? H2 : H1) + ((size_t)b * NN + (size_t)chunk * 256) * DD;
    const float4* src4 = (const float4*)src;
    int tid = threadIdx.x;
    float4 s = make_float4(0.f, 0.f, 0.f, 0.f);
    // 256 rows * 128 cols = 8192 float4; thread's column group = (tid & 31) * 4, fixed.
#pragma unroll 8
    for (int i = 0; i < 32; ++i) {
        float4 x = src4[i * 256 + tid];
        s.x += x.x; s.y += x.y; s.z += x.z; s.w += x.w;
    }
    // lanes l and l^32 cover the same columns -> one butterfly step
    s.x += __shfl_xor(s.x, 32);
    s.y += __shfl_xor(s.y, 32);
    s.z += __shfl_xor(s.z, 32);
    s.w += __shfl_xor(s.w, 32);
    __shared__ float red[4][32][4];
    int wave = tid >> 6, lane = tid & 63;
    if (lane < 32) {
        red[wave][lane][0] = s.x; red[wave][lane][1] = s.y;
        red[wave][lane][2] = s.z; red[wave][lane][3] = s.w;
    }
    __syncthreads();
    if (tid < 32) {
        float t0 = 0.f, t1 = 0.f, t2 = 0.f, t3 = 0.f;
#pragma unroll
        for (int w = 0; w < 4; ++w) {
            t0 += red[w][tid][0]; t1 += red[w][tid][1];
            t2 += red[w][tid][2]; t3 += red[w][tid][3];
        }
        float* dst = hsum + (size_t)(t * NB + b) * DD + tid * 4;
        atomicAdd(dst + 0, t0);
        atomicAdd(dst + 1, t1);
        atomicAdd(dst + 2, t2);
        atomicAdd(dst + 3, t3);
    }
}

// ---------------------------------------------------------------------------
// Kernel 2: v[p][b][k][d] = scale * sum_e W[k][d][e] * hsum[1-p][b][e]
// scale = 1/(N * sqrt(d)) folds the mean normalization and the softmax scale.
// grid 320 = 2 x 16 x 10, 128 threads (one per d).
__global__ __launch_bounds__(128) void k_v(const float* __restrict__ W1,
                                           const float* __restrict__ W2,
                                           const float* __restrict__ hsum,
                                           float* __restrict__ v) {
    int bi = blockIdx.x;
    int p = bi / 160;
    int rem = bi % 160;
    int b = rem / 10;
    int k = rem % 10;
    const float* W = (p ? W2 : W1) + (size_t)k * DD * DD;
    const float* hb = hsum + (size_t)((1 - p) * NB + b) * DD;  // path1 uses mean(H2), path2 mean(H1)
    __shared__ float4 h_s[32];
    int tid = threadIdx.x;
    if (tid < 32) h_s[tid] = ((const float4*)hb)[tid];
    __syncthreads();
    const float4* Wrow = (const float4*)(W + (size_t)tid * DD);
    float acc = 0.f;
#pragma unroll 8
    for (int e4 = 0; e4 < 32; ++e4) {
        float4 w4 = Wrow[e4];
        float4 h4 = h_s[e4];
        acc += w4.x * h4.x + w4.y * h4.y + w4.z * h4.z + w4.w * h4.w;
    }
    const float SCALE = (float)(1.0 / (16384.0 * 11.313708498984761));  // 1/(N*sqrt(128))
    v[((size_t)(p * NB + b) * KK + k) * DD + tid] = acc * SCALE;
}

// ---------------------------------------------------------------------------
// Kernel 3: scores + exp + weighted-X partial sums.
// grid 4096 = 2 paths x 16 batches x 128 tiles of 128 rows. 256 threads.
// 8 lanes per row (full 128-B line per row per load), 4 rows per thread-group.
__global__ __launch_bounds__(256) void k_scores(const float* __restrict__ H1,
                                                const float* __restrict__ H2,
                                                const float* __restrict__ X1,
                                                const float* __restrict__ X2,
                                                const float* __restrict__ v,
                                                float* __restrict__ accg) {
    int bi = blockIdx.x;
    int p = bi >> 11;
    int rem = bi & 2047;
    int b = rem >> 7;
    int tile = rem & 127;
    int row0 = tile << 7;
    const float* H = (p ? H2 : H1) + (size_t)b * NN * DD;
    const float* X = (p ? X2 : X1) + (size_t)b * NN * 3;
    const float* vp = v + (size_t)(p * NB + b) * KK * DD;

    __shared__ float4 v_s4[KK * DD / 4];   // 1280 floats
    __shared__ float red[4][40];
    float* v_s = (float*)v_s4;

    int tid = threadIdx.x;
    for (int i = tid; i < KK * DD / 4; i += 256)
        v_s4[i] = ((const float4*)vp)[i];
    __syncthreads();

    int g = tid >> 3;       // lane-group 0..31 (8 per wave)
    int l = tid & 7;        // lane within group -> d-slice
    int nbase = row0 + (g << 2);

    float accs[4][KK];
#pragma unroll
    for (int r = 0; r < 4; ++r)
#pragma unroll
        for (int k = 0; k < KK; ++k) accs[r][k] = 0.f;

#pragma unroll
    for (int j = 0; j < 4; ++j) {
        float4 h[4];
#pragma unroll
        for (int r = 0; r < 4; ++r)
            h[r] = *(const float4*)(H + (size_t)(nbase + r) * DD + (j << 5) + (l << 2));
#pragma unroll
        for (int k = 0; k < KK; ++k) {
            float4 vv = *(const float4*)(v_s + k * DD + (j << 5) + (l << 2));
#pragma unroll
            for (int r = 0; r < 4; ++r)
                accs[r][k] += h[r].x * vv.x + h[r].y * vv.y + h[r].z * vv.z + h[r].w * vv.w;
        }
    }
    // reduce the d-partials across the 8 lanes of the group (all lanes get the sum)
#pragma unroll
    for (int r = 0; r < 4; ++r)
#pragma unroll
        for (int k = 0; k < KK; ++k) {
            float s = accs[r][k];
            s += __shfl_xor(s, 1);
            s += __shfl_xor(s, 2);
            s += __shfl_xor(s, 4);
            accs[r][k] = s;
        }

    float pSE[KK], pY0[KK], pY1[KK], pY2[KK];
#pragma unroll
    for (int k = 0; k < KK; ++k) { pSE[k] = 0.f; pY0[k] = 0.f; pY1[k] = 0.f; pY2[k] = 0.f; }

    // |s| <~ 0.3, so exp without max-subtraction is exact softmax semantics.
#pragma unroll
    for (int r = 0; r < 4; ++r) {
        int n = nbase + r;
        float x0 = X[(size_t)n * 3 + 0];
        float x1 = X[(size_t)n * 3 + 1];
        float x2 = X[(size_t)n * 3 + 2];
#pragma unroll
        for (int k = 0; k < KK; ++k) {
            float e = __expf(accs[r][k]);
            pSE[k] += e;
            pY0[k] += e * x0;
            pY1[k] += e * x1;
            pY2[k] += e * x2;
        }
    }
    // 8 lanes per group hold identical partials; reduce across the 8 groups of the wave
#pragma unroll
    for (int k = 0; k < KK; ++k) {
        pSE[k] += __shfl_xor(pSE[k], 8);  pSE[k] += __shfl_xor(pSE[k], 16);  pSE[k] += __shfl_xor(pSE[k], 32);
        pY0[k] += __shfl_xor(pY0[k], 8);  pY0[k] += __shfl_xor(pY0[k], 16);  pY0[k] += __shfl_xor(pY0[k], 32);
        pY1[k] += __shfl_xor(pY1[k], 8);  pY1[k] += __shfl_xor(pY1[k], 16);  pY1[k] += __shfl_xor(pY1[k], 32);
        pY2[k] += __shfl_xor(pY2[k], 8);  pY2[k] += __shfl_xor(pY2[k], 16);  pY2[k] += __shfl_xor(pY2[k], 32);
    }
    int wave = tid >> 6, lane = tid & 63;
    if (lane == 0) {
#pragma unroll
        for (int k = 0; k < KK; ++k) {
            red[wave][k] = pSE[k];
            red[wave][10 + k] = pY0[k];
            red[wave][20 + k] = pY1[k];
            red[wave][30 + k] = pY2[k];
        }
    }
    __syncthreads();
    if (tid < 40) {
        float s = red[0][tid] + red[1][tid] + red[2][tid] + red[3][tid];
        atomicAdd(accg + (size_t)(p * NB + b) * 40 + tid, s);
    }
}

// ---------------------------------------------------------------------------
// Kernel 4: finalize Y1/Y2 and Kabsch alignment (fp64 one-sided Jacobi SVD).
// grid 16 (one per batch), 64 threads.
__global__ __launch_bounds__(64) void k_final(const float* __restrict__ accg,
                                              float* __restrict__ out) {
    int b = blockIdx.x;
    int tid = threadIdx.x;
    __shared__ float Ys[2][KK][3];
    if (tid < 2 * KK * 3) {
        int p = tid / 30;
        int r = tid % 30;
        int k = r / 3;
        int c = r % 3;
        const float* a = accg + (size_t)(p * NB + b) * 40;
        float val = a[10 + c * 10 + k] / a[k];
        Ys[p][k][c] = val;
        out[((size_t)(b * 3 + p) * KK + k) * 3 + c] = val;
    }
    __syncthreads();
    if (tid == 0) {
        double P[KK][3], Q[KK][3];
        double c1[3] = {0, 0, 0}, c2[3] = {0, 0, 0};
        for (int i = 0; i < KK; ++i)
            for (int c = 0; c < 3; ++c) {
                P[i][c] = (double)Ys[0][i][c];
                Q[i][c] = (double)Ys[1][i][c];
                c1[c] += P[i][c];
                c2[c] += Q[i][c];
            }
        for (int c = 0; c < 3; ++c) { c1[c] /= KK; c2[c] /= KK; }
        double A0[3][3];
        for (int a = 0; a < 3; ++a)
            for (int c = 0; c < 3; ++c) {
                double s = 0;
                for (int i = 0; i < KK; ++i) s += (P[i][a] - c1[a]) * (Q[i][c] - c2[c]);
                A0[a][c] = s;
            }
        // one-sided Jacobi SVD of A0: Bm = A0*V with orthogonal columns, u_j = Bm[:,j]/sig_j
        double Bm[3][3], V[3][3];
        for (int a = 0; a < 3; ++a)
            for (int c = 0; c < 3; ++c) { Bm[a][c] = A0[a][c]; V[a][c] = (a == c) ? 1.0 : 0.0; }
        for (int sweep = 0; sweep < 16; ++sweep)
            for (int p = 0; p < 2; ++p)
                for (int q = p + 1; q < 3; ++q) {
                    double al = 0, be = 0, ga = 0;
                    for (int r = 0; r < 3; ++r) {
                        al += Bm[r][p] * Bm[r][p];
                        be += Bm[r][q] * Bm[r][q];
                        ga += Bm[r][p] * Bm[r][q];
                    }
                    if (fabs(ga) < 1e-300) continue;
                    double zeta = (be - al) / (2.0 * ga);
                    double t = copysign(1.0, zeta) / (fabs(zeta) + sqrt(1.0 + zeta * zeta));
                    double cs = 1.0 / sqrt(1.0 + t * t);
                    double sn = cs * t;
                    for (int r = 0; r < 3; ++r) {
                        double bp = Bm[r][p], bq = Bm[r][q];
                        Bm[r][p] = cs * bp - sn * bq;
                        Bm[r][q] = sn * bp + cs * bq;
                        double vp = V[r][p], vq = V[r][q];
                        V[r][p] = cs * vp - sn * vq;
                        V[r][q] = sn * vp + cs * vq;
                    }
                }
        double sig[3];
        for (int j = 0; j < 3; ++j) {
            sig[j] = sqrt(Bm[0][j] * Bm[0][j] + Bm[1][j] * Bm[1][j] + Bm[2][j] * Bm[2][j]);
            if (sig[j] < 1e-300) sig[j] = 1e-300;
        }
        int jmin = 0;
        if (sig[1] < sig[jmin]) jmin = 1;
        if (sig[2] < sig[jmin]) jmin = 2;
        // sign(det(U @ Vt)) == sign(det(A0)) since det(A0) = det(U)*prod(sig)*det(Vt)
        double det = A0[0][0] * (A0[1][1] * A0[2][2] - A0[1][2] * A0[2][1])
                   - A0[0][1] * (A0[1][0] * A0[2][2] - A0[1][2] * A0[2][0])
                   + A0[0][2] * (A0[1][0] * A0[2][1] - A0[1][1] * A0[2][0]);
        double sgn = (det >= 0.0) ? 1.0 : -1.0;
        double R[3][3];
        for (int a = 0; a < 3; ++a)
            for (int c = 0; c < 3; ++c) {
                double s = 0;
                for (int j = 0; j < 3; ++j) {
                    double dj = (j == jmin) ? sgn : 1.0;
                    s += dj * (Bm[a][j] / sig[j]) * V[c][j];
                }
                R[a][c] = s;
            }
        for (int i = 0; i < KK; ++i)
            for (int c = 0; c < 3; ++c) {
                double s = c2[c];
                for (int a = 0; a < 3; ++a) s += (P[i][a] - c1[a]) * R[a][c];
                out[((size_t)(b * 3 + 2) * KK + i) * 3 + c] = (float)s;
            }
    }
}

// ---------------------------------------------------------------------------
extern "C" void kernel_launch(void* const* d_in, const int* in_sizes, int n_in,
                              void* d_out, int out_size, void* d_ws, size_t ws_size,
                              hipStream_t stream) {
    const float* H1 = (const float*)d_in[0];
    const float* H2 = (const float*)d_in[1];
    const float* X1 = (const float*)d_in[2];
    const float* X2 = (const float*)d_in[3];
    const float* W1 = (const float*)d_in[4];
    const float* W2 = (const float*)d_in[5];
    float* out = (float*)d_out;
    float* ws = (float*)d_ws;
    float* hsum = ws;              // 4096 floats
    float* v    = ws + 4096;       // 40960 floats
    float* accg = ws + 45056;      // 1280 floats

    hipMemsetAsync(d_ws, 0, WS_FLOATS * sizeof(float), stream);
    hipLaunchKernelGGL(k_means,  dim3(2048), dim3(256), 0, stream, H1, H2, hsum);
    hipLaunchKernelGGL(k_v,      dim3(320),  dim3(128), 0, stream, W1, W2, hsum, v);
    hipLaunchKernelGGL(k_scores, dim3(4096), dim3(256), 0, stream, H1, H2, X1, X2, v, accg);
    hipLaunchKernelGGL(k_final,  dim3(16),   dim3(64),  0, stream, accg, out);
}